// Round 1
// baseline (72.344 us; speedup 1.0000x reference)
//
#include <hip/hip_runtime.h>

#define HW 9216
#define W 96
#define H 96
#define NC 256
#define NT 49
#define EPSV 1e-5f

// -------- weight normalization: nw[t,p] = w[t,p] / (sum_t w[t,p] + eps) ----
__global__ __launch_bounds__(256) void norm_w_kernel(const float* __restrict__ w,
                                                     float* __restrict__ nw) {
    int p = blockIdx.x * 256 + threadIdx.x;
    if (p >= HW) return;
    float s = 0.f;
#pragma unroll
    for (int t = 0; t < NT; ++t) s += w[t * HW + p];
    float inv = 1.f / (s + EPSV);
#pragma unroll
    for (int t = 0; t < NT; ++t) nw[t * HW + p] = w[t * HW + p] * inv;
}

// -------- one message-passing step: y[c,p] = sum_t nw[t,p] * x_pad[c, p+off(t)]
// Block: 16x16 pixel tile, CC channels looped. 49 per-pixel weights live in
// registers (reused across CC channels); per-channel 22x22 halo staged in LDS.
// LDS row stride 24 -> exact 2-way bank aliasing (free on CDNA4).
#define TS 16
#define HSZ 22
#define HPAD 24
#define CC 8

__global__ __launch_bounds__(256) void step_kernel(const float* __restrict__ x,
                                                   const float* __restrict__ nw,
                                                   float* __restrict__ y) {
    __shared__ float xs[HSZ][HPAD];
    const int tx = threadIdx.x & 15;
    const int ty = threadIdx.x >> 4;
    const int bx = blockIdx.x * TS;
    const int by = blockIdx.y * TS;
    const int px = bx + tx;
    const int py = by + ty;
    const int p = py * W + px;

    float wreg[NT];
#pragma unroll
    for (int t = 0; t < NT; ++t) wreg[t] = nw[t * HW + p];

    const int cbase = blockIdx.z * CC;
    for (int cc = 0; cc < CC; ++cc) {
        const float* __restrict__ xc = x + (cbase + cc) * HW;
        __syncthreads();  // protect xs from previous iteration's readers
        for (int i = threadIdx.x; i < HSZ * HSZ; i += 256) {
            int hy = i / HSZ;
            int hx = i - hy * HSZ;
            int gy = by - 3 + hy;
            int gx = bx - 3 + hx;
            float v = 0.f;  // zero padding (jnp.pad)
            if ((unsigned)gy < (unsigned)H && (unsigned)gx < (unsigned)W)
                v = xc[gy * W + gx];
            xs[hy][hx] = v;
        }
        __syncthreads();
        float acc = 0.f;
#pragma unroll
        for (int i = 0; i < 7; ++i)
#pragma unroll
            for (int j = 0; j < 7; ++j)
                acc = fmaf(wreg[i * 7 + j], xs[ty + i][tx + j], acc);
        y[(cbase + cc) * HW + p] = acc;
    }
}

// -------- 1x1 conv: 256 -> 3 ------------------------------------------------
__global__ __launch_bounds__(256) void conv_kernel(const float* __restrict__ x,
                                                   const float* __restrict__ cw,
                                                   const float* __restrict__ cb,
                                                   float* __restrict__ y) {
    int p = blockIdx.x * 256 + threadIdx.x;
    if (p >= HW) return;
    float a0 = cb[0], a1 = cb[1], a2 = cb[2];
#pragma unroll 8
    for (int c = 0; c < NC; ++c) {
        float v = x[c * HW + p];
        a0 = fmaf(v, cw[c], a0);
        a1 = fmaf(v, cw[NC + c], a1);
        a2 = fmaf(v, cw[2 * NC + c], a2);
    }
    y[p] = a0;
    y[HW + p] = a1;
    y[2 * HW + p] = a2;
}

// -------- bilinear x4 upsample, half-pixel centers, edge clamp --------------
#define OUTS 384
__global__ __launch_bounds__(256) void upsample_kernel(const float* __restrict__ src,
                                                       float* __restrict__ dst) {
    int idx = blockIdx.x * 256 + threadIdx.x;
    if (idx >= 3 * OUTS * OUTS) return;
    int xo = idx % OUTS;
    int t = idx / OUTS;
    int yo = t % OUTS;
    int ch = t / OUTS;
    float sx = xo * 0.25f - 0.375f;  // (xo+0.5)*0.25 - 0.5
    float sy = yo * 0.25f - 0.375f;
    float fxf = floorf(sx), fyf = floorf(sy);
    int x0 = (int)fxf, y0 = (int)fyf;
    float fx = sx - fxf, fy = sy - fyf;
    int x0c = max(x0, 0), x1c = min(x0 + 1, W - 1);
    int y0c = max(y0, 0), y1c = min(y0 + 1, H - 1);
    const float* __restrict__ s = src + ch * HW;
    float v00 = s[y0c * W + x0c], v01 = s[y0c * W + x1c];
    float v10 = s[y1c * W + x0c], v11 = s[y1c * W + x1c];
    float v0 = v00 + (v01 - v00) * fx;
    float v1 = v10 + (v11 - v10) * fx;
    dst[idx] = v0 + (v1 - v0) * fy;
}

extern "C" void kernel_launch(void* const* d_in, const int* in_sizes, int n_in,
                              void* d_out, int out_size, void* d_ws, size_t ws_size,
                              hipStream_t stream) {
    const float* input  = (const float*)d_in[0];   // (1,256,96,96)
    const float* weight = (const float*)d_in[1];   // (1,49,9216)
    const float* conv_w = (const float*)d_in[2];   // (3,256)
    const float* conv_b = (const float*)d_in[3];   // (3,)
    float* out = (float*)d_out;                    // (1,3,384,384)

    float* ws = (float*)d_ws;
    float* nw = ws;                    // 49*9216      = 451584
    float* x1 = nw + NT * HW;          // 256*9216     = 2359296
    float* x2 = x1 + NC * HW;          // 256*9216
    float* cv = x2 + NC * HW;          // 3*9216

    norm_w_kernel<<<(HW + 255) / 256, 256, 0, stream>>>(weight, nw);

    dim3 g(W / TS, H / TS, NC / CC);   // (6,6,32)
    step_kernel<<<g, 256, 0, stream>>>(input, nw, x1);
    step_kernel<<<g, 256, 0, stream>>>(x1, nw, x2);

    conv_kernel<<<(HW + 255) / 256, 256, 0, stream>>>(x2, conv_w, conv_b, cv);

    upsample_kernel<<<(3 * OUTS * OUTS + 255) / 256, 256, 0, stream>>>(cv, out);
}

// Round 2
// 60.465 us; speedup vs baseline: 1.1965x; 1.1965x over previous
//
#include <hip/hip_runtime.h>

#define HW 9216
#define W 96
#define H 96
#define NC 256
#define NT 49
#define EPSV 1e-5f

#define TS 16
#define HSZ 22
#define HPAD 24
#define CC 8
#define NZ (NC / CC)   // 32 z-blocks

// -------- step 1: fused weight-normalize + message passing ------------------
// y[c,p] = sum_t (w[t,p]/(sum_t' w[t',p]+eps)) * x_pad[c, p+off(t)]
__global__ __launch_bounds__(256) void step1_kernel(const float* __restrict__ x,
                                                    const float* __restrict__ w,
                                                    float* __restrict__ y) {
    __shared__ float xs[CC][HSZ][HPAD];  // 8*22*24*4 = 16896 B
    const int tx = threadIdx.x & 15;
    const int ty = threadIdx.x >> 4;
    const int bx = blockIdx.x * TS;
    const int by = blockIdx.y * TS;
    const int px = bx + tx;
    const int py = by + ty;
    const int p = py * W + px;

    // load + normalize the 49 per-pixel weights in registers
    float wreg[NT];
    float s = 0.f;
#pragma unroll
    for (int t = 0; t < NT; ++t) { wreg[t] = w[t * HW + p]; s += wreg[t]; }
    const float inv = 1.f / (s + EPSV);
#pragma unroll
    for (int t = 0; t < NT; ++t) wreg[t] *= inv;

    // stage all 8 channels' 22x22 halos (zero-padded) — ONE barrier per block
    const int cbase = blockIdx.z * CC;
    for (int i = threadIdx.x; i < CC * HSZ * HSZ; i += 256) {
        int c = i / (HSZ * HSZ);
        int r = i - c * (HSZ * HSZ);
        int hy = r / HSZ;
        int hx = r - hy * HSZ;
        int gy = by - 3 + hy;
        int gx = bx - 3 + hx;
        float v = 0.f;
        if ((unsigned)gy < (unsigned)H && (unsigned)gx < (unsigned)W)
            v = x[(cbase + c) * HW + gy * W + gx];
        xs[c][hy][hx] = v;
    }
    __syncthreads();

#pragma unroll
    for (int cc = 0; cc < CC; ++cc) {
        float acc = 0.f;
#pragma unroll
        for (int i = 0; i < 7; ++i)
#pragma unroll
            for (int j = 0; j < 7; ++j)
                acc = fmaf(wreg[i * 7 + j], xs[cc][ty + i][tx + j], acc);
        y[(cbase + cc) * HW + p] = acc;
    }
}

// -------- step 2: fused normalize + message passing + partial 1x1 conv ------
// emits partial[z][o][p] = sum_{c in chunk z} conv_w[o,c] * y2[c,p]
__global__ __launch_bounds__(256) void step2_kernel(const float* __restrict__ x,
                                                    const float* __restrict__ w,
                                                    const float* __restrict__ cw,
                                                    float* __restrict__ partial) {
    __shared__ float xs[CC][HSZ][HPAD];
    const int tx = threadIdx.x & 15;
    const int ty = threadIdx.x >> 4;
    const int bx = blockIdx.x * TS;
    const int by = blockIdx.y * TS;
    const int px = bx + tx;
    const int py = by + ty;
    const int p = py * W + px;

    float wreg[NT];
    float s = 0.f;
#pragma unroll
    for (int t = 0; t < NT; ++t) { wreg[t] = w[t * HW + p]; s += wreg[t]; }
    const float inv = 1.f / (s + EPSV);
#pragma unroll
    for (int t = 0; t < NT; ++t) wreg[t] *= inv;

    const int cbase = blockIdx.z * CC;
    for (int i = threadIdx.x; i < CC * HSZ * HSZ; i += 256) {
        int c = i / (HSZ * HSZ);
        int r = i - c * (HSZ * HSZ);
        int hy = r / HSZ;
        int hx = r - hy * HSZ;
        int gy = by - 3 + hy;
        int gx = bx - 3 + hx;
        float v = 0.f;
        if ((unsigned)gy < (unsigned)H && (unsigned)gx < (unsigned)W)
            v = x[(cbase + c) * HW + gy * W + gx];
        xs[c][hy][hx] = v;
    }
    __syncthreads();

    float o0 = 0.f, o1 = 0.f, o2 = 0.f;
#pragma unroll
    for (int cc = 0; cc < CC; ++cc) {
        float acc = 0.f;
#pragma unroll
        for (int i = 0; i < 7; ++i)
#pragma unroll
            for (int j = 0; j < 7; ++j)
                acc = fmaf(wreg[i * 7 + j], xs[cc][ty + i][tx + j], acc);
        const int c = cbase + cc;
        o0 = fmaf(acc, cw[c], o0);
        o1 = fmaf(acc, cw[NC + c], o1);
        o2 = fmaf(acc, cw[2 * NC + c], o2);
    }
    const int z = blockIdx.z;
    partial[(z * 3 + 0) * HW + p] = o0;
    partial[(z * 3 + 1) * HW + p] = o1;
    partial[(z * 3 + 2) * HW + p] = o2;
}

// -------- reduce partials + bias --------------------------------------------
__global__ __launch_bounds__(256) void reduce_kernel(const float* __restrict__ partial,
                                                     const float* __restrict__ cb,
                                                     float* __restrict__ cv) {
    int idx = blockIdx.x * 256 + threadIdx.x;  // 3*HW
    if (idx >= 3 * HW) return;
    int o = idx / HW;
    int p = idx - o * HW;
    float s = cb[o];
#pragma unroll
    for (int z = 0; z < NZ; ++z) s += partial[(z * 3 + o) * HW + p];
    cv[idx] = s;
}

// -------- bilinear x4 upsample, half-pixel centers, edge clamp --------------
#define OUTS 384
__global__ __launch_bounds__(256) void upsample_kernel(const float* __restrict__ src,
                                                       float* __restrict__ dst) {
    int idx = blockIdx.x * 256 + threadIdx.x;
    if (idx >= 3 * OUTS * OUTS) return;
    int xo = idx % OUTS;
    int t = idx / OUTS;
    int yo = t % OUTS;
    int ch = t / OUTS;
    float sx = xo * 0.25f - 0.375f;  // (xo+0.5)*0.25 - 0.5
    float sy = yo * 0.25f - 0.375f;
    float fxf = floorf(sx), fyf = floorf(sy);
    int x0 = (int)fxf, y0 = (int)fyf;
    float fx = sx - fxf, fy = sy - fyf;
    int x0c = max(x0, 0), x1c = min(x0 + 1, W - 1);
    int y0c = max(y0, 0), y1c = min(y0 + 1, H - 1);
    const float* __restrict__ s = src + ch * HW;
    float v00 = s[y0c * W + x0c], v01 = s[y0c * W + x1c];
    float v10 = s[y1c * W + x0c], v11 = s[y1c * W + x1c];
    float v0 = v00 + (v01 - v00) * fx;
    float v1 = v10 + (v11 - v10) * fx;
    dst[idx] = v0 + (v1 - v0) * fy;
}

extern "C" void kernel_launch(void* const* d_in, const int* in_sizes, int n_in,
                              void* d_out, int out_size, void* d_ws, size_t ws_size,
                              hipStream_t stream) {
    const float* input  = (const float*)d_in[0];   // (1,256,96,96)
    const float* weight = (const float*)d_in[1];   // (1,49,9216)
    const float* conv_w = (const float*)d_in[2];   // (3,256)
    const float* conv_b = (const float*)d_in[3];   // (3,)
    float* out = (float*)d_out;                    // (1,3,384,384)

    float* ws = (float*)d_ws;
    float* x1      = ws;                      // 256*9216 = 2359296
    float* partial = x1 + NC * HW;            // 32*3*9216 = 884736
    float* cv      = partial + NZ * 3 * HW;   // 3*9216

    dim3 g(W / TS, H / TS, NZ);               // (6,6,32)
    step1_kernel<<<g, 256, 0, stream>>>(input, weight, x1);
    step2_kernel<<<g, 256, 0, stream>>>(x1, weight, conv_w, partial);

    reduce_kernel<<<(3 * HW + 255) / 256, 256, 0, stream>>>(partial, conv_b, cv);
    upsample_kernel<<<(3 * OUTS * OUTS + 255) / 256, 256, 0, stream>>>(cv, out);
}

// Round 3
// 40.003 us; speedup vs baseline: 1.8085x; 1.5115x over previous
//
#include <hip/hip_runtime.h>

#define HW 9216
#define W 96
#define H 96
#define NC 256
#define NT 49
#define EPSV 1e-5f

#define TS 16
#define HSZ 22
#define CC 8
#define NZ (NC / CC)   // 32 z-blocks

// ---- fused normalize + message passing step --------------------------------
// LDS layout: xs4[g][hy][hx] = float4 of channels [cbase+4g .. cbase+4g+3]
// at halo position (hy,hx). Tap read = 1 ds_read_b128 + 4 FMA (weight bcast).
template <int FUSE_CONV>
__global__ __launch_bounds__(256) void step_kernel(const float* __restrict__ x,
                                                   const float* __restrict__ w,
                                                   const float* __restrict__ cw,
                                                   float* __restrict__ y) {
    __shared__ float4 xs4[2][HSZ][HSZ];  // 2*484*16 = 15488 B
    const int tx = threadIdx.x & 15;
    const int ty = threadIdx.x >> 4;
    const int bx = blockIdx.x * TS;
    const int by = blockIdx.y * TS;
    const int px = bx + tx;
    const int py = by + ty;
    const int p = py * W + px;

    // load + normalize the 49 per-pixel weights in registers
    float wreg[NT];
    float s = 0.f;
#pragma unroll
    for (int t = 0; t < NT; ++t) { wreg[t] = w[t * HW + p]; s += wreg[t]; }
    const float inv = 1.f / (s + EPSV);
#pragma unroll
    for (int t = 0; t < NT; ++t) wreg[t] *= inv;

    // stage 8 channels' 22x22 halos as two float4 planes (zero-padded)
    const int cbase = blockIdx.z * CC;
    const float* __restrict__ xb = x + cbase * HW;
    for (int i = threadIdx.x; i < 2 * HSZ * HSZ; i += 256) {
        int g = (i >= HSZ * HSZ) ? 1 : 0;
        int pix = i - g * (HSZ * HSZ);
        int hy = pix / HSZ;
        int hx = pix - hy * HSZ;
        int gy = by - 3 + hy;
        int gx = bx - 3 + hx;
        float4 v = {0.f, 0.f, 0.f, 0.f};
        if ((unsigned)gy < (unsigned)H && (unsigned)gx < (unsigned)W) {
            const float* sp = xb + (g * 4) * HW + gy * W + gx;
            v.x = sp[0]; v.y = sp[HW]; v.z = sp[2 * HW]; v.w = sp[3 * HW];
        }
        xs4[g][hy][hx] = v;
    }
    __syncthreads();

    float4 a0 = {0.f, 0.f, 0.f, 0.f};
    float4 a1 = {0.f, 0.f, 0.f, 0.f};
#pragma unroll
    for (int i = 0; i < 7; ++i) {
#pragma unroll
        for (int j = 0; j < 7; ++j) {
            const float wv = wreg[i * 7 + j];
            const float4 v0 = xs4[0][ty + i][tx + j];
            a0.x = fmaf(wv, v0.x, a0.x);
            a0.y = fmaf(wv, v0.y, a0.y);
            a0.z = fmaf(wv, v0.z, a0.z);
            a0.w = fmaf(wv, v0.w, a0.w);
            const float4 v1 = xs4[1][ty + i][tx + j];
            a1.x = fmaf(wv, v1.x, a1.x);
            a1.y = fmaf(wv, v1.y, a1.y);
            a1.z = fmaf(wv, v1.z, a1.z);
            a1.w = fmaf(wv, v1.w, a1.w);
        }
    }

    if (FUSE_CONV) {
        // partial 1x1 conv: partial[z][o][p]
        float o0 = 0.f, o1 = 0.f, o2 = 0.f;
        const float acc[8] = {a0.x, a0.y, a0.z, a0.w, a1.x, a1.y, a1.z, a1.w};
#pragma unroll
        for (int k = 0; k < 8; ++k) {
            const int c = cbase + k;
            o0 = fmaf(acc[k], cw[c], o0);
            o1 = fmaf(acc[k], cw[NC + c], o1);
            o2 = fmaf(acc[k], cw[2 * NC + c], o2);
        }
        const int z = blockIdx.z;
        y[(z * 3 + 0) * HW + p] = o0;
        y[(z * 3 + 1) * HW + p] = o1;
        y[(z * 3 + 2) * HW + p] = o2;
    } else {
        y[(cbase + 0) * HW + p] = a0.x;
        y[(cbase + 1) * HW + p] = a0.y;
        y[(cbase + 2) * HW + p] = a0.z;
        y[(cbase + 3) * HW + p] = a0.w;
        y[(cbase + 4) * HW + p] = a1.x;
        y[(cbase + 5) * HW + p] = a1.y;
        y[(cbase + 6) * HW + p] = a1.z;
        y[(cbase + 7) * HW + p] = a1.w;
    }
}

// ---- fused z-reduce + bias + bilinear x4 upsample --------------------------
// Block: 32x32 output tile, 3 channels. Stages the 10x10x3 source patch
// (reduced over 32 z-partials) in LDS, then samples it.
#define OUTS 384
#define SRCP 10
__global__ __launch_bounds__(256) void upsample_kernel(const float* __restrict__ partial,
                                                       const float* __restrict__ cb,
                                                       float* __restrict__ dst) {
    __shared__ float cvs[3][SRCP][SRCP];  // 1200 B
    const int X = blockIdx.x * 32;        // output tile origin
    const int Y = blockIdx.y * 32;
    const int x0s = X >> 2;               // src tile origin
    const int y0s = Y >> 2;

    // reduce partials for the staged patch
    for (int e = threadIdx.x; e < 3 * SRCP * SRCP; e += 256) {
        int ch = e / (SRCP * SRCP);
        int r = e - ch * (SRCP * SRCP);
        int sy = r / SRCP;
        int sx = r - sy * SRCP;
        int gy = min(max(y0s - 1 + sy, 0), H - 1);
        int gx = min(max(x0s - 1 + sx, 0), W - 1);
        const int p = gy * W + gx;
        float sum = cb[ch];
#pragma unroll
        for (int z = 0; z < NZ; ++z) sum += partial[(z * 3 + ch) * HW + p];
        cvs[ch][sy][sx] = sum;
    }
    __syncthreads();

    const int xl = threadIdx.x & 31;
    const int yl0 = threadIdx.x >> 5;  // 0..7
    const int xo = X + xl;
    const float sxf = xo * 0.25f - 0.375f;
    const float fxf = floorf(sxf);
    const int jx = (int)fxf - (x0s - 1);
    const float fx = sxf - fxf;

#pragma unroll
    for (int k = 0; k < 4; ++k) {
        const int yo = Y + yl0 + 8 * k;
        const float syf = yo * 0.25f - 0.375f;
        const float fyf = floorf(syf);
        const int jy = (int)fyf - (y0s - 1);
        const float fy = syf - fyf;
#pragma unroll
        for (int ch = 0; ch < 3; ++ch) {
            const float v00 = cvs[ch][jy][jx], v01 = cvs[ch][jy][jx + 1];
            const float v10 = cvs[ch][jy + 1][jx], v11 = cvs[ch][jy + 1][jx + 1];
            const float v0 = v00 + (v01 - v00) * fx;
            const float v1 = v10 + (v11 - v10) * fx;
            dst[ch * OUTS * OUTS + yo * OUTS + xo] = v0 + (v1 - v0) * fy;
        }
    }
}

extern "C" void kernel_launch(void* const* d_in, const int* in_sizes, int n_in,
                              void* d_out, int out_size, void* d_ws, size_t ws_size,
                              hipStream_t stream) {
    const float* input  = (const float*)d_in[0];   // (1,256,96,96)
    const float* weight = (const float*)d_in[1];   // (1,49,9216)
    const float* conv_w = (const float*)d_in[2];   // (3,256)
    const float* conv_b = (const float*)d_in[3];   // (3,)
    float* out = (float*)d_out;                    // (1,3,384,384)

    float* ws = (float*)d_ws;
    float* x1      = ws;                      // 256*9216
    float* partial = x1 + NC * HW;            // 32*3*9216

    dim3 g(W / TS, H / TS, NZ);               // (6,6,32)
    step_kernel<0><<<g, 256, 0, stream>>>(input, weight, nullptr, x1);
    step_kernel<1><<<g, 256, 0, stream>>>(x1, weight, conv_w, partial);

    dim3 gu(OUTS / 32, OUTS / 32);            // (12,12)
    upsample_kernel<<<gu, 256, 0, stream>>>(partial, conv_b, out);
}